// Round 4
// baseline (287.469 us; speedup 1.0000x reference)
//
#include <hip/hip_runtime.h>
#include <math.h>

typedef __attribute__((ext_vector_type(8))) short short8;
typedef __attribute__((ext_vector_type(4))) float float4v;

#define D_DIM 256
#define K_EMB 1024
#define HW_SZ 1024
#define N_TOT 32768
#define SMP_B (D_DIM * HW_SZ)  // per-batch stride in X (floats)

// ---- bf16 hi/lo split helpers (RNE) ----
__device__ __forceinline__ unsigned short f2bf(float x) {
  unsigned int u = __builtin_bit_cast(unsigned int, x);
  return (unsigned short)((u + 0x7fffu + ((u >> 16) & 1u)) >> 16);
}
__device__ __forceinline__ float bf2f(unsigned short h) {
  unsigned int u = ((unsigned int)h) << 16;
  return __builtin_bit_cast(float, u);
}

// ---- async global->LDS, 16B/lane (dest = wave-uniform base + lane*16) ----
typedef const __attribute__((address_space(1))) void GV;
typedef __attribute__((address_space(3))) void LV;
__device__ __forceinline__ void async16(const void* g, void* l) {
  __builtin_amdgcn_global_load_lds((GV*)g, (LV*)l, 16, 0, 0);
}

// ------------------------------------------------------------------ prep ----
// blocks 0..127: E -> Ehi/Elo bf16 + enorm (exact fp32).
// blocks 128..2175: X [b][d][hw] -> Xt_hi/Xt_lo [n][d] bf16 + Sum(x^2) scalar.
__global__ __launch_bounds__(256) void vq_prep(
    const float* __restrict__ X, const float* __restrict__ E,
    unsigned short* __restrict__ Xh, unsigned short* __restrict__ Xl,
    unsigned short* __restrict__ Ehi, unsigned short* __restrict__ Elo,
    float* __restrict__ enorm, float* __restrict__ xnormsum) {
  const int t = threadIdx.x;
  const int bi = blockIdx.x;

  if (bi < 128) {  // ---- E prep ----
    int tid = bi * 256 + t;  // 32768 threads, 32 per code
    int c = tid >> 5;
    int d0 = (tid & 31) * 8;
    const float* p = E + c * D_DIM + d0;
    float s = 0.f;
    short8 hv, lv;
#pragma unroll
    for (int j = 0; j < 8; ++j) {
      float x = p[j];
      s = fmaf(x, x, s);
      unsigned short h = f2bf(x);
      hv[j] = (short)h;
      lv[j] = (short)f2bf(x - bf2f(h));
    }
    *(short8*)(Ehi + c * D_DIM + d0) = hv;
    *(short8*)(Elo + c * D_DIM + d0) = lv;
#pragma unroll
    for (int off = 1; off <= 16; off <<= 1) s += __shfl_xor(s, off);
    if ((tid & 31) == 0) enorm[c] = s;
    return;
  }

  // ---- X prep: 64d x 64hw tile per block through LDS ----
  __shared__ float ts[64][65];  // +1 pad
  __shared__ float xp[4];
  const int bx = bi - 128;
  const int b = bx >> 6;
  const int dt = (bx >> 4) & 3;
  const int ht = bx & 15;
  const int d0 = dt * 64;
  const int hw0 = ht * 64;

  float s = 0.f;
  {
    const int dl = t >> 4;
    const int hl = (t & 15) * 4;
#pragma unroll
    for (int i = 0; i < 4; ++i) {
      float4 v = *(const float4*)(X + b * SMP_B + (d0 + dl + i * 16) * HW_SZ + hw0 + hl);
      ts[dl + i * 16][hl + 0] = v.x;
      ts[dl + i * 16][hl + 1] = v.y;
      ts[dl + i * 16][hl + 2] = v.z;
      ts[dl + i * 16][hl + 3] = v.w;
      s = fmaf(v.x, v.x, s);
      s = fmaf(v.y, v.y, s);
      s = fmaf(v.z, v.z, s);
      s = fmaf(v.w, v.w, s);
    }
  }
  __syncthreads();
#pragma unroll
  for (int p = 0; p < 2; ++p) {
    const int c = t + p * 256;
    const int dch = c & 7;   // d chunk of 8
    const int nl = c >> 3;   // 0..63
    short8 hv, lv;
#pragma unroll
    for (int j = 0; j < 8; ++j) {
      float x = ts[dch * 8 + j][nl];
      unsigned short h = f2bf(x);
      hv[j] = (short)h;
      lv[j] = (short)f2bf(x - bf2f(h));
    }
    const int n = b * 1024 + hw0 + nl;
    *(short8*)(Xh + n * D_DIM + d0 + dch * 8) = hv;
    *(short8*)(Xl + n * D_DIM + d0 + dch * 8) = lv;
  }
  // block-reduce Sum(x^2) -> one atomic
#pragma unroll
  for (int off = 32; off >= 1; off >>= 1) s += __shfl_xor(s, off);
  if ((t & 63) == 0) xp[t >> 6] = s;
  __syncthreads();
  if (t == 0) atomicAdd(xnormsum, xp[0] + xp[1] + xp[2] + xp[3]);
}

// ------------------------------------------------------------------ gemm ----
// Per block: 128 codes (M) x 128 samples (N), D=256 in BK=32 chunks.
// LDS exactly 32 KB (rv/ri overlaid on dead tiles) -> 4+ blocks/CU.
__global__ __launch_bounds__(256, 4) void vq_gemm(
    const unsigned short* __restrict__ Xh, const unsigned short* __restrict__ Xl,
    const unsigned short* __restrict__ Ehi, const unsigned short* __restrict__ Elo,
    const float* __restrict__ enorm, float* __restrict__ pval, int* __restrict__ pidx) {
  __shared__ unsigned short smem[16384];  // 32768 B exactly
  unsigned short* es_hi = smem;           // [128*32] 8 KB each
  unsigned short* es_lo = smem + 4096;
  unsigned short* xs_hi = smem + 8192;
  unsigned short* xs_lo = smem + 12288;

  const int t = threadIdx.x;
  const int i = blockIdx.x;
  // XCD-aware swizzle: all 8 code-stripes of one sample-block share i&7 -> same XCD
  const int cblk = (i >> 3) & 7;               // code stripe 0..7
  const int sblk = ((i >> 6) << 3) | (i & 7);  // sample block 0..255
  const int n0 = sblk * 128;

  const int lane = t & 63;
  const int wv = t >> 6;
  const int wm = wv >> 1;  // code half
  const int wn = wv & 1;   // sample half
  const int l15 = lane & 15;
  const int q = lane >> 4;

  float4v acc[4][4];
#pragma unroll
  for (int a = 0; a < 4; ++a)
#pragma unroll
    for (int c = 0; c < 4; ++c) acc[a][c] = {0.f, 0.f, 0.f, 0.f};

  const int srow = t >> 2;       // 0..63
  const int scol = (t & 3) * 8;  // 0,8,16,24
  const unsigned short* xhb = Xh + (n0 + srow) * D_DIM + scol;
  const unsigned short* xlb = Xl + (n0 + srow) * D_DIM + scol;
  const unsigned short* ehb = Ehi + (cblk * 128 + srow) * D_DIM + scol;
  const unsigned short* elb = Elo + (cblk * 128 + srow) * D_DIM + scol;
  char* xh_b = (char*)xs_hi;
  char* xl_b = (char*)xs_lo;
  char* eh_b = (char*)es_hi;
  char* el_b = (char*)es_lo;
  const int dst0 = t * 16;

  for (int dc = 0; dc < 8; ++dc) {
    const int d0 = dc * 32;
    async16(xhb + d0, xh_b + dst0);
    async16(xhb + 64 * D_DIM + d0, xh_b + dst0 + 4096);
    async16(xlb + d0, xl_b + dst0);
    async16(xlb + 64 * D_DIM + d0, xl_b + dst0 + 4096);
    async16(ehb + d0, eh_b + dst0);
    async16(ehb + 64 * D_DIM + d0, eh_b + dst0 + 4096);
    async16(elb + d0, el_b + dst0);
    async16(elb + 64 * D_DIM + d0, el_b + dst0 + 4096);
    __syncthreads();  // barrier drains vmcnt -> tiles visible

    short8 ah[4], al[4], xh[4], xl[4];
#pragma unroll
    for (int mi = 0; mi < 4; ++mi) {
      int row = wm * 64 + mi * 16 + l15;
      ah[mi] = *(const short8*)&es_hi[row * 32 + q * 8];
      al[mi] = *(const short8*)&es_lo[row * 32 + q * 8];
    }
#pragma unroll
    for (int ni = 0; ni < 4; ++ni) {
      int row = wn * 64 + ni * 16 + l15;
      xh[ni] = *(const short8*)&xs_hi[row * 32 + q * 8];
      xl[ni] = *(const short8*)&xs_lo[row * 32 + q * 8];
    }
#pragma unroll
    for (int mi = 0; mi < 4; ++mi)
#pragma unroll
      for (int ni = 0; ni < 4; ++ni)
        acc[mi][ni] = __builtin_amdgcn_mfma_f32_16x16x32_bf16(ah[mi], xh[ni], acc[mi][ni], 0, 0, 0);
#pragma unroll
    for (int mi = 0; mi < 4; ++mi)
#pragma unroll
      for (int ni = 0; ni < 4; ++ni)
        acc[mi][ni] = __builtin_amdgcn_mfma_f32_16x16x32_bf16(ah[mi], xl[ni], acc[mi][ni], 0, 0, 0);
#pragma unroll
    for (int mi = 0; mi < 4; ++mi)
#pragma unroll
      for (int ni = 0; ni < 4; ++ni)
        acc[mi][ni] = __builtin_amdgcn_mfma_f32_16x16x32_bf16(al[mi], xh[ni], acc[mi][ni], 0, 0, 0);
    __syncthreads();  // all frag reads done before next stage overwrites
  }

  // ---- per-sample argmin over this block's 128 codes ----
  // Overlay reductions on dead tile LDS (last frag reads fenced by loop barrier).
  float(*rv)[128] = (float(*)[128])smem;             // 1 KB @ byte 0
  int(*ri)[128] = (int(*)[128])(smem + 2048);        // 1 KB @ byte 4096

  float4 en[4];
#pragma unroll
  for (int mi = 0; mi < 4; ++mi)
    en[mi] = *(const float4*)&enorm[cblk * 128 + wm * 64 + mi * 16 + q * 4];

#pragma unroll
  for (int ni = 0; ni < 4; ++ni) {
    float bv = 1e30f;
    int bc = 0;
#pragma unroll
    for (int mi = 0; mi < 4; ++mi) {
      const float* enp = (const float*)&en[mi];
#pragma unroll
      for (int r = 0; r < 4; ++r) {
        float v = fmaf(-2.f, acc[mi][ni][r], enp[r]);
        if (v < bv) { bv = v; bc = wm * 64 + mi * 16 + q * 4 + r; }  // ascending c
      }
    }
#pragma unroll
    for (int off = 16; off <= 32; off <<= 1) {  // merge the 4 q-groups
      float ov = __shfl_xor(bv, off);
      int oc = __shfl_xor(bc, off);
      if (ov < bv || (ov == bv && oc < bc)) { bv = ov; bc = oc; }
    }
    if (q == 0) {
      rv[wm][wn * 64 + ni * 16 + l15] = bv;
      ri[wm][wn * 64 + ni * 16 + l15] = cblk * 128 + bc;
    }
  }
  __syncthreads();
  if (t < 128) {  // merge code halves (wm0 codes < wm1 codes: tie keeps wm0)
    float v0 = rv[0][t];
    int c0 = ri[0][t];
    float v1 = rv[1][t];
    int c1 = ri[1][t];
    if (v1 < v0) { v0 = v1; c0 = c1; }
    pval[cblk * N_TOT + sblk * 128 + t] = v0;
    pidx[cblk * N_TOT + sblk * 128 + t] = c0;
  }
}

// ------------------------------------- epilogue + fused finalize (ticket) ----
__global__ __launch_bounds__(256) void vq_epi(
    const float* __restrict__ E, const float* __restrict__ pval,
    const int* __restrict__ pidx, float* __restrict__ out,
    float* __restrict__ counts, float* __restrict__ lossacc,
    const float* __restrict__ xnormsum, unsigned int* __restrict__ ticket,
    float* __restrict__ out_tail) {
  __shared__ int best_idx[64];
  __shared__ float es[64][257];  // 64.3 KB: gathered best-code rows
  __shared__ float fpart[4];
  __shared__ unsigned int rank_s;
  const int t = threadIdx.x;
  const int n0 = blockIdx.x * 64;
  const int b = n0 >> 10;
  const int hw0 = n0 & 1023;

  if (t < 64) {
    int n = n0 + t;
    float bv = 1e30f;
    int bc = 0;
#pragma unroll
    for (int s = 0; s < 8; ++s) {  // ascending stripe = ascending code range
      float v = pval[s * N_TOT + n];
      int c = pidx[s * N_TOT + n];
      if (v < bv || (v == bv && c < bc)) { bv = v; bc = c; }
    }
    best_idx[t] = bc;
    atomicAdd(&counts[bc], 1.0f);
    // loss contribution: ||e-x||^2 = bestval + ||x||^2 (xnorm summed in prep)
    float ls = bv;
#pragma unroll
    for (int off = 32; off >= 1; off >>= 1) ls += __shfl_xor(ls, off);
    if (t == 0) atomicAdd(lossacc, ls);
  }
  __syncthreads();

  // gather the 64 best-code E rows into LDS (coalesced 1KB/wave global reads)
#pragma unroll
  for (int i = 0; i < 16; ++i) {
    const int c = t + i * 256;
    const int r = c >> 6;  // wave-uniform row
    const int col = (c & 63) * 4;
    float4 v = *(const float4*)(E + best_idx[r] * D_DIM + col);
    es[r][col + 0] = v.x;
    es[r][col + 1] = v.y;
    es[r][col + 2] = v.z;
    es[r][col + 3] = v.w;
  }
  __syncthreads();

  // write quantized output (no X read needed)
  const int nl4 = (t & 15) * 4;
  const int drow = t >> 4;
  float* Op = out + b * SMP_B + hw0 + nl4;
#pragma unroll 4
  for (int d = drow; d < D_DIM; d += 16) {
    float4 qv;
    qv.x = es[nl4 + 0][d];
    qv.y = es[nl4 + 1][d];
    qv.z = es[nl4 + 2][d];
    qv.w = es[nl4 + 3][d];
    *(float4*)(Op + d * HW_SZ) = qv;
  }

  // ---- last-block finalize ----
  __threadfence();  // make this block's atomics/stores visible device-wide
  if (t == 0)
    rank_s = __hip_atomic_fetch_add(ticket, 1u, __ATOMIC_ACQ_REL, __HIP_MEMORY_SCOPE_AGENT);
  __syncthreads();
  if (rank_s == gridDim.x - 1) {
    float s = 0.f;
    for (int k = t; k < K_EMB; k += 256) {
      float c = __hip_atomic_load(&counts[k], __ATOMIC_RELAXED, __HIP_MEMORY_SCOPE_AGENT);
      float p = c * (1.0f / 32768.0f);
      s = fmaf(p, logf(p + 1e-10f), s);  // p==0 -> 0*log(1e-10)==0, matches ref
    }
#pragma unroll
    for (int off = 32; off >= 1; off >>= 1) s += __shfl_xor(s, off);
    if ((t & 63) == 0) fpart[t >> 6] = s;
    __syncthreads();
    if (t == 0) {
      float tot = fpart[0] + fpart[1] + fpart[2] + fpart[3];
      float la = __hip_atomic_load(lossacc, __ATOMIC_RELAXED, __HIP_MEMORY_SCOPE_AGENT);
      float xn = __hip_atomic_load((float*)xnormsum, __ATOMIC_RELAXED, __HIP_MEMORY_SCOPE_AGENT);
      out_tail[0] = 1.25f * (la + xn) * (1.0f / 8388608.0f);
      out_tail[1] = expf(-tot);
    }
  }
}

// ---------------------------------------------------------------- launch ----
extern "C" void kernel_launch(void* const* d_in, const int* in_sizes, int n_in,
                              void* d_out, int out_size, void* d_ws, size_t ws_size,
                              hipStream_t stream) {
  const float* X = (const float*)d_in[0];  // [32,256,32,32]
  const float* E = (const float*)d_in[1];  // [1024,256]
  float* out = (float*)d_out;              // 8388608 + 2
  float* ws = (float*)d_ws;

  // d_out doubles as scratch for transposed bf16 X (exactly 8388608 floats);
  // vq_epi fully overwrites it afterwards with the real output.
  unsigned short* Xh = (unsigned short*)out;  // [32768][256] bf16
  unsigned short* Xl = Xh + N_TOT * D_DIM;    // [32768][256] bf16

  unsigned short* Ehi = (unsigned short*)ws;        // 512 KB
  unsigned short* Elo = Ehi + 262144;               // 512 KB
  float* enorm = ws + 262144;                       // [1024]
  float* counts = ws + 263168;                      // [1024]
  float* lossa = ws + 264192;                       // [1]
  float* xnorms = ws + 264193;                      // [1]
  unsigned int* ticket = (unsigned int*)(ws + 264194);  // [1]
  float* pval = ws + 264256;                        // [8*32768]
  int* pidx = (int*)(ws + 264256 + 262144);         // [8*32768]

  hipMemsetAsync(counts, 0, 1027 * sizeof(float), stream);  // counts+loss+xnorm+ticket
  vq_prep<<<2176, 256, 0, stream>>>(X, E, Xh, Xl, Ehi, Elo, enorm, xnorms);
  vq_gemm<<<2048, 256, 0, stream>>>(Xh, Xl, Ehi, Elo, enorm, pval, pidx);
  vq_epi<<<512, 256, 0, stream>>>(E, pval, pidx, out, counts, lossa, xnorms, ticket,
                                  out + 8388608);
}

// Round 5
// 189.665 us; speedup vs baseline: 1.5157x; 1.5157x over previous
//
#include <hip/hip_runtime.h>
#include <math.h>

typedef __attribute__((ext_vector_type(8))) short short8;
typedef __attribute__((ext_vector_type(4))) float float4v;

#define D_DIM 256
#define K_EMB 1024
#define HW_SZ 1024
#define N_TOT 32768
#define SMP_B (D_DIM * HW_SZ)  // per-batch stride in X (floats)

// ---- bf16 hi/lo split helpers (RNE) ----
__device__ __forceinline__ unsigned short f2bf(float x) {
  unsigned int u = __builtin_bit_cast(unsigned int, x);
  return (unsigned short)((u + 0x7fffu + ((u >> 16) & 1u)) >> 16);
}
__device__ __forceinline__ float bf2f(unsigned short h) {
  unsigned int u = ((unsigned int)h) << 16;
  return __builtin_bit_cast(float, u);
}

// ---- async global->LDS, 16B/lane (dest = wave-uniform base + lane*16) ----
typedef const __attribute__((address_space(1))) void GV;
typedef __attribute__((address_space(3))) void LV;
__device__ __forceinline__ void async16(const void* g, void* l) {
  __builtin_amdgcn_global_load_lds((GV*)g, (LV*)l, 16, 0, 0);
}

// ------------------------------------------------------------------ prep ----
// blocks 0..127: E -> Ehi/Elo bf16 + enorm (exact fp32).
// blocks 128..2175: X [b][d][hw] -> Xt_hi/Xt_lo [n][d] bf16 + Sum(x^2) scalar.
__global__ __launch_bounds__(256) void vq_prep(
    const float* __restrict__ X, const float* __restrict__ E,
    unsigned short* __restrict__ Xh, unsigned short* __restrict__ Xl,
    unsigned short* __restrict__ Ehi, unsigned short* __restrict__ Elo,
    float* __restrict__ enorm, float* __restrict__ xnormsum) {
  const int t = threadIdx.x;
  const int bi = blockIdx.x;

  if (bi < 128) {  // ---- E prep ----
    int tid = bi * 256 + t;  // 32768 threads, 32 per code
    int c = tid >> 5;
    int d0 = (tid & 31) * 8;
    const float* p = E + c * D_DIM + d0;
    float s = 0.f;
    short8 hv, lv;
#pragma unroll
    for (int j = 0; j < 8; ++j) {
      float x = p[j];
      s = fmaf(x, x, s);
      unsigned short h = f2bf(x);
      hv[j] = (short)h;
      lv[j] = (short)f2bf(x - bf2f(h));
    }
    *(short8*)(Ehi + c * D_DIM + d0) = hv;
    *(short8*)(Elo + c * D_DIM + d0) = lv;
#pragma unroll
    for (int off = 1; off <= 16; off <<= 1) s += __shfl_xor(s, off);
    if ((tid & 31) == 0) enorm[c] = s;
    return;
  }

  // ---- X prep: 64d x 64hw tile per block through LDS ----
  __shared__ float ts[64][65];  // +1 pad
  __shared__ float xp[4];
  const int bx = bi - 128;
  const int b = bx >> 6;
  const int dt = (bx >> 4) & 3;
  const int ht = bx & 15;
  const int d0 = dt * 64;
  const int hw0 = ht * 64;

  float s = 0.f;
  {
    const int dl = t >> 4;
    const int hl = (t & 15) * 4;
#pragma unroll
    for (int i = 0; i < 4; ++i) {
      float4 v = *(const float4*)(X + b * SMP_B + (d0 + dl + i * 16) * HW_SZ + hw0 + hl);
      ts[dl + i * 16][hl + 0] = v.x;
      ts[dl + i * 16][hl + 1] = v.y;
      ts[dl + i * 16][hl + 2] = v.z;
      ts[dl + i * 16][hl + 3] = v.w;
      s = fmaf(v.x, v.x, s);
      s = fmaf(v.y, v.y, s);
      s = fmaf(v.z, v.z, s);
      s = fmaf(v.w, v.w, s);
    }
  }
  __syncthreads();
#pragma unroll
  for (int p = 0; p < 2; ++p) {
    const int c = t + p * 256;
    const int dch = c & 7;   // d chunk of 8
    const int nl = c >> 3;   // 0..63
    short8 hv, lv;
#pragma unroll
    for (int j = 0; j < 8; ++j) {
      float x = ts[dch * 8 + j][nl];
      unsigned short h = f2bf(x);
      hv[j] = (short)h;
      lv[j] = (short)f2bf(x - bf2f(h));
    }
    const int n = b * 1024 + hw0 + nl;
    *(short8*)(Xh + n * D_DIM + d0 + dch * 8) = hv;
    *(short8*)(Xl + n * D_DIM + d0 + dch * 8) = lv;
  }
  // block-reduce Sum(x^2) -> one atomic
#pragma unroll
  for (int off = 32; off >= 1; off >>= 1) s += __shfl_xor(s, off);
  if ((t & 63) == 0) xp[t >> 6] = s;
  __syncthreads();
  if (t == 0) atomicAdd(xnormsum, xp[0] + xp[1] + xp[2] + xp[3]);
}

// ------------------------------------------------------------------ gemm ----
// Per block: 128 codes (M) x 128 samples (N), D=256 in BK=32 chunks.
// LDS exactly 32 KB (rv/ri overlaid on dead tiles) -> 4 blocks/CU.
__global__ __launch_bounds__(256, 4) void vq_gemm(
    const unsigned short* __restrict__ Xh, const unsigned short* __restrict__ Xl,
    const unsigned short* __restrict__ Ehi, const unsigned short* __restrict__ Elo,
    const float* __restrict__ enorm, float* __restrict__ pval, int* __restrict__ pidx) {
  __shared__ unsigned short smem[16384];  // 32768 B exactly
  unsigned short* es_hi = smem;           // [128*32] 8 KB each
  unsigned short* es_lo = smem + 4096;
  unsigned short* xs_hi = smem + 8192;
  unsigned short* xs_lo = smem + 12288;

  const int t = threadIdx.x;
  const int i = blockIdx.x;
  // XCD-aware swizzle: all 8 code-stripes of one sample-block share i&7 -> same XCD
  const int cblk = (i >> 3) & 7;               // code stripe 0..7
  const int sblk = ((i >> 6) << 3) | (i & 7);  // sample block 0..255
  const int n0 = sblk * 128;

  const int lane = t & 63;
  const int wv = t >> 6;
  const int wm = wv >> 1;  // code half
  const int wn = wv & 1;   // sample half
  const int l15 = lane & 15;
  const int q = lane >> 4;

  float4v acc[4][4];
#pragma unroll
  for (int a = 0; a < 4; ++a)
#pragma unroll
    for (int c = 0; c < 4; ++c) acc[a][c] = {0.f, 0.f, 0.f, 0.f};

  const int srow = t >> 2;       // 0..63
  const int scol = (t & 3) * 8;  // 0,8,16,24
  const unsigned short* xhb = Xh + (n0 + srow) * D_DIM + scol;
  const unsigned short* xlb = Xl + (n0 + srow) * D_DIM + scol;
  const unsigned short* ehb = Ehi + (cblk * 128 + srow) * D_DIM + scol;
  const unsigned short* elb = Elo + (cblk * 128 + srow) * D_DIM + scol;
  char* xh_b = (char*)xs_hi;
  char* xl_b = (char*)xs_lo;
  char* eh_b = (char*)es_hi;
  char* el_b = (char*)es_lo;
  const int dst0 = t * 16;

  for (int dc = 0; dc < 8; ++dc) {
    const int d0 = dc * 32;
    async16(xhb + d0, xh_b + dst0);
    async16(xhb + 64 * D_DIM + d0, xh_b + dst0 + 4096);
    async16(xlb + d0, xl_b + dst0);
    async16(xlb + 64 * D_DIM + d0, xl_b + dst0 + 4096);
    async16(ehb + d0, eh_b + dst0);
    async16(ehb + 64 * D_DIM + d0, eh_b + dst0 + 4096);
    async16(elb + d0, el_b + dst0);
    async16(elb + 64 * D_DIM + d0, el_b + dst0 + 4096);
    __syncthreads();  // barrier drains vmcnt -> tiles visible

    short8 ah[4], al[4], xh[4], xl[4];
#pragma unroll
    for (int mi = 0; mi < 4; ++mi) {
      int row = wm * 64 + mi * 16 + l15;
      ah[mi] = *(const short8*)&es_hi[row * 32 + q * 8];
      al[mi] = *(const short8*)&es_lo[row * 32 + q * 8];
    }
#pragma unroll
    for (int ni = 0; ni < 4; ++ni) {
      int row = wn * 64 + ni * 16 + l15;
      xh[ni] = *(const short8*)&xs_hi[row * 32 + q * 8];
      xl[ni] = *(const short8*)&xs_lo[row * 32 + q * 8];
    }
#pragma unroll
    for (int mi = 0; mi < 4; ++mi)
#pragma unroll
      for (int ni = 0; ni < 4; ++ni)
        acc[mi][ni] = __builtin_amdgcn_mfma_f32_16x16x32_bf16(ah[mi], xh[ni], acc[mi][ni], 0, 0, 0);
#pragma unroll
    for (int mi = 0; mi < 4; ++mi)
#pragma unroll
      for (int ni = 0; ni < 4; ++ni)
        acc[mi][ni] = __builtin_amdgcn_mfma_f32_16x16x32_bf16(ah[mi], xl[ni], acc[mi][ni], 0, 0, 0);
#pragma unroll
    for (int mi = 0; mi < 4; ++mi)
#pragma unroll
      for (int ni = 0; ni < 4; ++ni)
        acc[mi][ni] = __builtin_amdgcn_mfma_f32_16x16x32_bf16(al[mi], xh[ni], acc[mi][ni], 0, 0, 0);
    __syncthreads();  // all frag reads done before next stage overwrites
  }

  // ---- per-sample argmin over this block's 128 codes ----
  // Overlay reductions on dead tile LDS (last frag reads fenced by loop barrier).
  float(*rv)[128] = (float(*)[128])smem;       // 1 KB @ byte 0
  int(*ri)[128] = (int(*)[128])(smem + 2048);  // 1 KB @ byte 4096

  float4 en[4];
#pragma unroll
  for (int mi = 0; mi < 4; ++mi)
    en[mi] = *(const float4*)&enorm[cblk * 128 + wm * 64 + mi * 16 + q * 4];

#pragma unroll
  for (int ni = 0; ni < 4; ++ni) {
    float bv = 1e30f;
    int bc = 0;
#pragma unroll
    for (int mi = 0; mi < 4; ++mi) {
      const float* enp = (const float*)&en[mi];
#pragma unroll
      for (int r = 0; r < 4; ++r) {
        float v = fmaf(-2.f, acc[mi][ni][r], enp[r]);
        if (v < bv) { bv = v; bc = wm * 64 + mi * 16 + q * 4 + r; }  // ascending c
      }
    }
#pragma unroll
    for (int off = 16; off <= 32; off <<= 1) {  // merge the 4 q-groups
      float ov = __shfl_xor(bv, off);
      int oc = __shfl_xor(bc, off);
      if (ov < bv || (ov == bv && oc < bc)) { bv = ov; bc = oc; }
    }
    if (q == 0) {
      rv[wm][wn * 64 + ni * 16 + l15] = bv;
      ri[wm][wn * 64 + ni * 16 + l15] = cblk * 128 + bc;
    }
  }
  __syncthreads();
  if (t < 128) {  // merge code halves (wm0 codes < wm1 codes: tie keeps wm0)
    float v0 = rv[0][t];
    int c0 = ri[0][t];
    float v1 = rv[1][t];
    int c1 = ri[1][t];
    if (v1 < v0) { v0 = v1; c0 = c1; }
    pval[cblk * N_TOT + sblk * 128 + t] = v0;
    pidx[cblk * N_TOT + sblk * 128 + t] = c0;
  }
}

// -------------------------------------------------------------- epilogue ----
// No device-scope fences here: cross-kernel visibility for counts/loss comes
// from the dispatch boundary (round-4 lesson: a per-block __threadfence on
// multi-XCD CDNA4 forces serialized L2 writebacks -> 2.4x write amplification).
__global__ __launch_bounds__(256) void vq_epi(
    const float* __restrict__ E, const float* __restrict__ pval,
    const int* __restrict__ pidx, float* __restrict__ out,
    float* __restrict__ counts, float* __restrict__ lossacc) {
  __shared__ int best_idx[64];
  __shared__ float es[64][257];  // gathered best-code rows
  const int t = threadIdx.x;
  const int n0 = blockIdx.x * 64;
  const int b = n0 >> 10;
  const int hw0 = n0 & 1023;

  if (t < 64) {
    int n = n0 + t;
    float bv = 1e30f;
    int bc = 0;
#pragma unroll
    for (int s = 0; s < 8; ++s) {  // ascending stripe = ascending code range
      float v = pval[s * N_TOT + n];
      int c = pidx[s * N_TOT + n];
      if (v < bv || (v == bv && c < bc)) { bv = v; bc = c; }
    }
    best_idx[t] = bc;
    atomicAdd(&counts[bc], 1.0f);
    // loss contribution: ||e-x||^2 = bestval + ||x||^2 (xnorm summed in prep)
    float ls = bv;
#pragma unroll
    for (int off = 32; off >= 1; off >>= 1) ls += __shfl_xor(ls, off);
    if (t == 0) atomicAdd(lossacc, ls);
  }
  __syncthreads();

  // gather the 64 best-code E rows into LDS (coalesced 1KB/wave global reads)
#pragma unroll
  for (int i = 0; i < 16; ++i) {
    const int c = t + i * 256;
    const int r = c >> 6;  // wave-uniform row
    const int col = (c & 63) * 4;
    float4 v = *(const float4*)(E + best_idx[r] * D_DIM + col);
    es[r][col + 0] = v.x;
    es[r][col + 1] = v.y;
    es[r][col + 2] = v.z;
    es[r][col + 3] = v.w;
  }
  __syncthreads();

  // write quantized output (no X read needed)
  const int nl4 = (t & 15) * 4;
  const int drow = t >> 4;
  float* Op = out + b * SMP_B + hw0 + nl4;
#pragma unroll 4
  for (int d = drow; d < D_DIM; d += 16) {
    float4 qv;
    qv.x = es[nl4 + 0][d];
    qv.y = es[nl4 + 1][d];
    qv.z = es[nl4 + 2][d];
    qv.w = es[nl4 + 3][d];
    *(float4*)(Op + d * HW_SZ) = qv;
  }
}

// -------------------------------------------------------------- finalize ----
__global__ __launch_bounds__(256) void vq_finalize(const float* __restrict__ counts,
                                                   const float* __restrict__ lossacc,
                                                   const float* __restrict__ xnormsum,
                                                   float* __restrict__ out_tail) {
  __shared__ float part[4];
  const int t = threadIdx.x;
  float s = 0.f;
#pragma unroll
  for (int k = t; k < K_EMB; k += 256) {
    float p = counts[k] * (1.0f / 32768.0f);
    s = fmaf(p, logf(p + 1e-10f), s);  // p==0 -> 0*log(1e-10)==0, matches ref
  }
#pragma unroll
  for (int off = 32; off >= 1; off >>= 1) s += __shfl_xor(s, off);
  if ((t & 63) == 0) part[t >> 6] = s;
  __syncthreads();
  if (t == 0) {
    float tot = part[0] + part[1] + part[2] + part[3];
    out_tail[0] = 1.25f * (lossacc[0] + xnormsum[0]) * (1.0f / 8388608.0f);
    out_tail[1] = expf(-tot);
  }
}

// ---------------------------------------------------------------- launch ----
extern "C" void kernel_launch(void* const* d_in, const int* in_sizes, int n_in,
                              void* d_out, int out_size, void* d_ws, size_t ws_size,
                              hipStream_t stream) {
  const float* X = (const float*)d_in[0];  // [32,256,32,32]
  const float* E = (const float*)d_in[1];  // [1024,256]
  float* out = (float*)d_out;              // 8388608 + 2
  float* ws = (float*)d_ws;

  // d_out doubles as scratch for transposed bf16 X (exactly 8388608 floats);
  // vq_epi fully overwrites it afterwards with the real output.
  unsigned short* Xh = (unsigned short*)out;  // [32768][256] bf16
  unsigned short* Xl = Xh + N_TOT * D_DIM;    // [32768][256] bf16

  unsigned short* Ehi = (unsigned short*)ws;  // 512 KB
  unsigned short* Elo = Ehi + 262144;         // 512 KB
  float* enorm = ws + 262144;                 // [1024]
  float* counts = ws + 263168;                // [1024]
  float* lossa = ws + 264192;                 // [1]
  float* xnorms = ws + 264193;                // [1]
  float* pval = ws + 264256;                  // [8*32768]
  int* pidx = (int*)(ws + 264256 + 262144);   // [8*32768]

  hipMemsetAsync(counts, 0, 1026 * sizeof(float), stream);  // counts+loss+xnorm
  vq_prep<<<2176, 256, 0, stream>>>(X, E, Xh, Xl, Ehi, Elo, enorm, xnorms);
  vq_gemm<<<2048, 256, 0, stream>>>(Xh, Xl, Ehi, Elo, enorm, pval, pidx);
  vq_epi<<<512, 256, 0, stream>>>(E, pval, pidx, out, counts, lossa);
  vq_finalize<<<1, 256, 0, stream>>>(counts, lossa, xnorms, out + 8388608);
}

// Round 6
// 170.048 us; speedup vs baseline: 1.6905x; 1.1154x over previous
//
#include <hip/hip_runtime.h>
#include <math.h>

typedef __attribute__((ext_vector_type(8))) short short8;
typedef __attribute__((ext_vector_type(4))) float float4v;

#define D_DIM 256
#define K_EMB 1024
#define HW_SZ 1024
#define N_TOT 32768
#define SMP_B (D_DIM * HW_SZ)  // per-batch stride in X (floats)

// ---- bf16 helper (RNE) ----
__device__ __forceinline__ unsigned short f2bf(float x) {
  unsigned int u = __builtin_bit_cast(unsigned int, x);
  return (unsigned short)((u + 0x7fffu + ((u >> 16) & 1u)) >> 16);
}

// ---- async global->LDS, 16B/lane (dest = wave-uniform base + lane*16) ----
typedef const __attribute__((address_space(1))) void GV;
typedef __attribute__((address_space(3))) void LV;
__device__ __forceinline__ void async16(const void* g, void* l) {
  __builtin_amdgcn_global_load_lds((GV*)g, (LV*)l, 16, 0, 0);
}

// ------------------------------------------------------------------ prep ----
// blocks 0..127: E -> Ehi bf16 + enorm (exact fp32); block 0 also zeroes accums.
// blocks 128..2175: X [b][d][hw] -> Xh [n][d] bf16 + Sum(x^2) scalar.
__global__ __launch_bounds__(256) void vq_prep(
    const float* __restrict__ X, const float* __restrict__ E,
    unsigned short* __restrict__ Xh, unsigned short* __restrict__ Ehi,
    float* __restrict__ enorm, float* __restrict__ zero_base,
    float* __restrict__ xnormsum) {
  const int t = threadIdx.x;
  const int bi = blockIdx.x;

  if (bi < 128) {  // ---- E prep ----
    if (bi == 0) {  // zero counts[1024] + lossacc + xnormsum (visible at next dispatch)
#pragma unroll
      for (int k = t; k < 1026; k += 256) zero_base[k] = 0.f;
    }
    int tid = bi * 256 + t;  // 32768 threads, 8 elements per thread
    int c = tid >> 5;
    int d0 = (tid & 31) * 8;
    const float* p = E + c * D_DIM + d0;
    float s = 0.f;
    short8 hv;
#pragma unroll
    for (int j = 0; j < 8; ++j) {
      float x = p[j];
      s = fmaf(x, x, s);
      hv[j] = (short)f2bf(x);
    }
    *(short8*)(Ehi + c * D_DIM + d0) = hv;
#pragma unroll
    for (int off = 1; off <= 16; off <<= 1) s += __shfl_xor(s, off);
    if ((tid & 31) == 0) enorm[c] = s;
    return;
  }

  // ---- X prep: 64d x 64hw tile per block through LDS ----
  __shared__ float ts[64][65];  // +1 pad
  __shared__ float xp[4];
  const int bx = bi - 128;
  const int b = bx >> 6;
  const int dt = (bx >> 4) & 3;
  const int ht = bx & 15;
  const int d0 = dt * 64;
  const int hw0 = ht * 64;

  float s = 0.f;
  {
    const int dl = t >> 4;
    const int hl = (t & 15) * 4;
#pragma unroll
    for (int i = 0; i < 4; ++i) {
      float4 v = *(const float4*)(X + b * SMP_B + (d0 + dl + i * 16) * HW_SZ + hw0 + hl);
      ts[dl + i * 16][hl + 0] = v.x;
      ts[dl + i * 16][hl + 1] = v.y;
      ts[dl + i * 16][hl + 2] = v.z;
      ts[dl + i * 16][hl + 3] = v.w;
      s = fmaf(v.x, v.x, s);
      s = fmaf(v.y, v.y, s);
      s = fmaf(v.z, v.z, s);
      s = fmaf(v.w, v.w, s);
    }
  }
  __syncthreads();
#pragma unroll
  for (int p = 0; p < 2; ++p) {
    const int c = t + p * 256;
    const int dch = c & 7;   // d chunk of 8
    const int nl = c >> 3;   // 0..63
    short8 hv;
#pragma unroll
    for (int j = 0; j < 8; ++j) hv[j] = (short)f2bf(ts[dch * 8 + j][nl]);
    const int n = b * 1024 + hw0 + nl;
    *(short8*)(Xh + n * D_DIM + d0 + dch * 8) = hv;
  }
  // block-reduce Sum(x^2) -> one atomic
#pragma unroll
  for (int off = 32; off >= 1; off >>= 1) s += __shfl_xor(s, off);
  if ((t & 63) == 0) xp[t >> 6] = s;
  __syncthreads();
  if (t == 0) atomicAdd(xnormsum, xp[0] + xp[1] + xp[2] + xp[3]);
}

// ------------------------------------------------------------------ gemm ----
// Per block: 128 codes (M) x 128 samples (N), D=256 in BK=32 chunks, pure bf16.
// LDS 16 KB; K-segment XOR swizzle (seg stored at q^(row&3)) spreads the
// row-stride-64B b128 frag reads from 8-way to ~4-way bank aliasing.
__global__ __launch_bounds__(256, 4) void vq_gemm(
    const unsigned short* __restrict__ Xh, const unsigned short* __restrict__ Ehi,
    const float* __restrict__ enorm, float* __restrict__ pval, int* __restrict__ pidx) {
  __shared__ unsigned short smem[8192];  // 16384 B: es 8 KB @0, xs 8 KB @8 KB
  unsigned short* es = smem;
  unsigned short* xs = smem + 4096;

  const int t = threadIdx.x;
  const int i = blockIdx.x;
  // XCD-aware swizzle: all 8 code-stripes of one sample-block share i&7 -> same XCD
  const int cblk = (i >> 3) & 7;               // code stripe 0..7
  const int sblk = ((i >> 6) << 3) | (i & 7);  // sample block 0..255
  const int n0 = sblk * 128;

  const int lane = t & 63;
  const int wv = t >> 6;
  const int wm = wv >> 1;  // code half
  const int wn = wv & 1;   // sample half
  const int l15 = lane & 15;
  const int q = lane >> 4;

  float4v acc[4][4];
#pragma unroll
  for (int a = 0; a < 4; ++a)
#pragma unroll
    for (int c = 0; c < 4; ++c) acc[a][c] = {0.f, 0.f, 0.f, 0.f};

  const int srow = t >> 2;                    // 0..63
  const int sseg = (t & 3) ^ (srow & 3);      // XOR-swizzled source K-segment
  const unsigned short* xhb = Xh + (n0 + srow) * D_DIM + sseg * 8;
  const unsigned short* ehb = Ehi + (cblk * 128 + srow) * D_DIM + sseg * 8;
  char* xs_b = (char*)xs;
  char* es_b = (char*)es;
  const int dst0 = t * 16;

  const int qa = ((q ^ (l15 & 3)) << 3);  // swizzled K-segment for frag reads

  for (int dc = 0; dc < 8; ++dc) {
    const int d0 = dc * 32;
    async16(ehb + d0, es_b + dst0);
    async16(ehb + 64 * D_DIM + d0, es_b + dst0 + 4096);
    async16(xhb + d0, xs_b + dst0);
    async16(xhb + 64 * D_DIM + d0, xs_b + dst0 + 4096);
    __syncthreads();  // barrier drains vmcnt -> tiles visible

    short8 ah[4], xh[4];
#pragma unroll
    for (int mi = 0; mi < 4; ++mi)
      ah[mi] = *(const short8*)&es[(wm * 64 + mi * 16 + l15) * 32 + qa];
#pragma unroll
    for (int ni = 0; ni < 4; ++ni)
      xh[ni] = *(const short8*)&xs[(wn * 64 + ni * 16 + l15) * 32 + qa];
#pragma unroll
    for (int mi = 0; mi < 4; ++mi)
#pragma unroll
      for (int ni = 0; ni < 4; ++ni)
        acc[mi][ni] = __builtin_amdgcn_mfma_f32_16x16x32_bf16(ah[mi], xh[ni], acc[mi][ni], 0, 0, 0);
    __syncthreads();  // all frag reads done before next stage overwrites
  }

  // ---- per-sample argmin over this block's 128 codes ----
  float(*rv)[128] = (float(*)[128])smem;       // overlay on dead tiles
  int(*ri)[128] = (int(*)[128])(smem + 2048);

  float4 en[4];
#pragma unroll
  for (int mi = 0; mi < 4; ++mi)
    en[mi] = *(const float4*)&enorm[cblk * 128 + wm * 64 + mi * 16 + q * 4];

#pragma unroll
  for (int ni = 0; ni < 4; ++ni) {
    float bv = 1e30f;
    int bc = 0;
#pragma unroll
    for (int mi = 0; mi < 4; ++mi) {
      const float* enp = (const float*)&en[mi];
#pragma unroll
      for (int r = 0; r < 4; ++r) {
        float v = fmaf(-2.f, acc[mi][ni][r], enp[r]);
        if (v < bv) { bv = v; bc = wm * 64 + mi * 16 + q * 4 + r; }  // ascending c
      }
    }
#pragma unroll
    for (int off = 16; off <= 32; off <<= 1) {  // merge the 4 q-groups
      float ov = __shfl_xor(bv, off);
      int oc = __shfl_xor(bc, off);
      if (ov < bv || (ov == bv && oc < bc)) { bv = ov; bc = oc; }
    }
    if (q == 0) {
      rv[wm][wn * 64 + ni * 16 + l15] = bv;
      ri[wm][wn * 64 + ni * 16 + l15] = cblk * 128 + bc;
    }
  }
  __syncthreads();
  if (t < 128) {  // merge code halves (wm0 codes < wm1 codes: tie keeps wm0)
    float v0 = rv[0][t];
    int c0 = ri[0][t];
    float v1 = rv[1][t];
    int c1 = ri[1][t];
    if (v1 < v0) { v0 = v1; c0 = c1; }
    pval[cblk * N_TOT + sblk * 128 + t] = v0;
    pidx[cblk * N_TOT + sblk * 128 + t] = c0;
  }
}

// -------------------------------------------------------------- epilogue ----
// No device-scope fences (round-4 lesson: per-block __threadfence on multi-XCD
// CDNA4 serializes L2 writebacks). Cross-kernel visibility = dispatch boundary.
__global__ __launch_bounds__(256) void vq_epi(
    const float* __restrict__ E, const float* __restrict__ pval,
    const int* __restrict__ pidx, float* __restrict__ out,
    float* __restrict__ counts, float* __restrict__ lossacc) {
  __shared__ int best_idx[64];
  __shared__ float es[64][257];  // gathered best-code rows
  const int t = threadIdx.x;
  const int n0 = blockIdx.x * 64;
  const int b = n0 >> 10;
  const int hw0 = n0 & 1023;

  if (t < 64) {
    int n = n0 + t;
    float bv = 1e30f;
    int bc = 0;
#pragma unroll
    for (int s = 0; s < 8; ++s) {  // ascending stripe = ascending code range
      float v = pval[s * N_TOT + n];
      int c = pidx[s * N_TOT + n];
      if (v < bv || (v == bv && c < bc)) { bv = v; bc = c; }
    }
    best_idx[t] = bc;
    atomicAdd(&counts[bc], 1.0f);
    // loss contribution: ||e-x||^2 = bestval + ||x||^2 (xnorm summed in prep)
    float ls = bv;
#pragma unroll
    for (int off = 32; off >= 1; off >>= 1) ls += __shfl_xor(ls, off);
    if (t == 0) atomicAdd(lossacc, ls);
  }
  __syncthreads();

  // gather the 64 best-code E rows into LDS (coalesced 1KB/wave global reads)
#pragma unroll
  for (int i = 0; i < 16; ++i) {
    const int c = t + i * 256;
    const int r = c >> 6;  // wave-uniform row
    const int col = (c & 63) * 4;
    float4 v = *(const float4*)(E + best_idx[r] * D_DIM + col);
    es[r][col + 0] = v.x;
    es[r][col + 1] = v.y;
    es[r][col + 2] = v.z;
    es[r][col + 3] = v.w;
  }
  __syncthreads();

  // write quantized output (no X read needed)
  const int nl4 = (t & 15) * 4;
  const int drow = t >> 4;
  float* Op = out + b * SMP_B + hw0 + nl4;
#pragma unroll 4
  for (int d = drow; d < D_DIM; d += 16) {
    float4 qv;
    qv.x = es[nl4 + 0][d];
    qv.y = es[nl4 + 1][d];
    qv.z = es[nl4 + 2][d];
    qv.w = es[nl4 + 3][d];
    *(float4*)(Op + d * HW_SZ) = qv;
  }
}

// -------------------------------------------------------------- finalize ----
__global__ __launch_bounds__(256) void vq_finalize(const float* __restrict__ counts,
                                                   const float* __restrict__ lossacc,
                                                   const float* __restrict__ xnormsum,
                                                   float* __restrict__ out_tail) {
  __shared__ float part[4];
  const int t = threadIdx.x;
  float s = 0.f;
#pragma unroll
  for (int k = t; k < K_EMB; k += 256) {
    float p = counts[k] * (1.0f / 32768.0f);
    s = fmaf(p, logf(p + 1e-10f), s);  // p==0 -> 0*log(1e-10)==0, matches ref
  }
#pragma unroll
  for (int off = 32; off >= 1; off >>= 1) s += __shfl_xor(s, off);
  if ((t & 63) == 0) part[t >> 6] = s;
  __syncthreads();
  if (t == 0) {
    float tot = part[0] + part[1] + part[2] + part[3];
    out_tail[0] = 1.25f * (lossacc[0] + xnormsum[0]) * (1.0f / 8388608.0f);
    out_tail[1] = expf(-tot);
  }
}

// ---------------------------------------------------------------- launch ----
extern "C" void kernel_launch(void* const* d_in, const int* in_sizes, int n_in,
                              void* d_out, int out_size, void* d_ws, size_t ws_size,
                              hipStream_t stream) {
  const float* X = (const float*)d_in[0];  // [32,256,32,32]
  const float* E = (const float*)d_in[1];  // [1024,256]
  float* out = (float*)d_out;              // 8388608 + 2
  float* ws = (float*)d_ws;

  // d_out doubles as scratch for transposed bf16 X (first 16.8 MB);
  // vq_epi fully overwrites it afterwards with the real output.
  unsigned short* Xh = (unsigned short*)out;  // [32768][256] bf16

  unsigned short* Ehi = (unsigned short*)ws;  // [1024][256] bf16 = 512 KB
  float* enorm = ws + 131072;                 // [1024]
  float* counts = ws + 132096;                // [1024]
  float* lossa = ws + 133120;                 // [1]
  float* xnorms = ws + 133121;                // [1]
  float* pval = ws + 133184;                  // [8*32768]
  int* pidx = (int*)(ws + 133184 + 262144);   // [8*32768]

  // no memset: prep block 0 zeroes counts/lossa/xnorms (contiguous 1026 floats)
  vq_prep<<<2176, 256, 0, stream>>>(X, E, Xh, Ehi, enorm, counts, xnorms);
  vq_gemm<<<2048, 256, 0, stream>>>(Xh, Ehi, enorm, pval, pidx);
  vq_epi<<<512, 256, 0, stream>>>(E, pval, pidx, out, counts, lossa);
  vq_finalize<<<1, 256, 0, stream>>>(counts, lossa, xnorms, out + 8388608);
}

// Round 7
// 169.802 us; speedup vs baseline: 1.6930x; 1.0015x over previous
//
#include <hip/hip_runtime.h>
#include <math.h>

typedef __attribute__((ext_vector_type(8))) short short8;
typedef __attribute__((ext_vector_type(4))) float float4v;

#define D_DIM 256
#define K_EMB 1024
#define HW_SZ 1024
#define N_TOT 32768
#define SMP_B (D_DIM * HW_SZ)  // per-batch stride in X (floats)

// ---- bf16 helper (RNE) ----
__device__ __forceinline__ unsigned short f2bf(float x) {
  unsigned int u = __builtin_bit_cast(unsigned int, x);
  return (unsigned short)((u + 0x7fffu + ((u >> 16) & 1u)) >> 16);
}

// ---- async global->LDS, 16B/lane (dest = wave-uniform base + lane*16) ----
typedef const __attribute__((address_space(1))) void GV;
typedef __attribute__((address_space(3))) void LV;
__device__ __forceinline__ void async16(const void* g, void* l) {
  __builtin_amdgcn_global_load_lds((GV*)g, (LV*)l, 16, 0, 0);
}

// ---------------------------------------------------------------- prep E ----
// E -> Ehi bf16 [1024][256] + enorm fp32 (exact); block 0 zeroes accumulators.
__global__ __launch_bounds__(256) void vq_prep_e(const float* __restrict__ E,
                                                 unsigned short* __restrict__ Ehi,
                                                 float* __restrict__ enorm,
                                                 float* __restrict__ zero_base) {
  const int t = threadIdx.x;
  const int bi = blockIdx.x;
  if (bi == 0) {  // zero counts[1024] + lossacc (visible at next dispatch)
#pragma unroll
    for (int k = t; k < 1025; k += 256) zero_base[k] = 0.f;
  }
  int tid = bi * 256 + t;  // 32768 threads, 8 elements each
  int c = tid >> 5;
  int d0 = (tid & 31) * 8;
  const float* p = E + c * D_DIM + d0;
  float s = 0.f;
  short8 hv;
#pragma unroll
  for (int j = 0; j < 8; ++j) {
    float x = p[j];
    s = fmaf(x, x, s);
    hv[j] = (short)f2bf(x);
  }
  *(short8*)(Ehi + c * D_DIM + d0) = hv;
#pragma unroll
  for (int off = 1; off <= 16; off <<= 1) s += __shfl_xor(s, off);
  if ((tid & 31) == 0) enorm[c] = s;
}

// ------------------------------------------------------------------ main ----
// One block = 64 samples x ALL 1024 codes. Phase 1: X staged once through LDS,
// bf16 B-frags pinned in VGPRs (+ sum x^2). Phase 2: barrier-free K-loop —
// E-frags loaded directly from global (Ehi 512 KB = L2-resident per XCD), MFMA
// pipelined by the compiler via vmcnt (no __syncthreads in the hot loop).
// Fused epilogue: argmin merge, counts/loss atomics, output write from E.
__global__ __launch_bounds__(256, 3) void vq_main(
    const float* __restrict__ X, const float* __restrict__ E,
    const unsigned short* __restrict__ Ehi, const float* __restrict__ enorm,
    float* __restrict__ out, float* __restrict__ counts,
    float* __restrict__ lossacc) {
  __shared__ float ts[32 * 64];  // 8 KB X staging chunk [32 d][64 n]
  __shared__ float bvs[64];
  __shared__ int bcs[64];
  __shared__ float lred[4];

  const int t = threadIdx.x;
  const int n0 = blockIdx.x * 64;
  const int b = n0 >> 10;
  const int hw0 = n0 & 1023;
  const int lane = t & 63;
  const int wv = t >> 6;
  const int wm = wv >> 1;  // code half within 128-cblk (0: rows 0..63)
  const int wn = wv & 1;   // sample half (32 each)
  const int l15 = lane & 15;
  const int q = lane >> 4;

  // ---- phase 1: X -> bf16 fragments in registers ----
  short8 xfrag[2][8];
  float xsq = 0.f;
  const float* Xb = X + b * SMP_B + hw0;
  const int srow = t >> 4;        // 0..15
  const int sseg = (t & 15) * 4;  // float offset within 64-wide row
  for (int dc = 0; dc < 8; ++dc) {
    async16(Xb + (dc * 32 + srow) * HW_SZ + sseg, (char*)ts + t * 16);
    async16(Xb + (dc * 32 + 16 + srow) * HW_SZ + sseg, (char*)ts + 4096 + t * 16);
    __syncthreads();  // drains vmcnt -> tile visible
#pragma unroll
    for (int ni = 0; ni < 2; ++ni) {
      short8 hv;
#pragma unroll
      for (int j = 0; j < 8; ++j) {
        float x = ts[(q * 8 + j) * 64 + wn * 32 + ni * 16 + l15];
        if (wm == 0) xsq = fmaf(x, x, xsq);  // each elem hit by both wm waves
        hv[j] = (short)f2bf(x);
      }
      xfrag[ni][dc] = hv;
    }
    __syncthreads();
  }

  // ---- phase 2: barrier-free K-loop over 1024 codes ----
  float bestv[2] = {1e30f, 1e30f};
  int bestc[2] = {0, 0};
  const unsigned short* Eh0 = Ehi + (wm * 64 + l15) * D_DIM + q * 8;
  for (int cblk = 0; cblk < 8; ++cblk) {
    float4v acc[4][2];
#pragma unroll
    for (int mi = 0; mi < 4; ++mi)
#pragma unroll
      for (int ni = 0; ni < 2; ++ni) acc[mi][ni] = {0.f, 0.f, 0.f, 0.f};
#pragma unroll
    for (int dc = 0; dc < 8; ++dc) {
      short8 ah[4];
#pragma unroll
      for (int mi = 0; mi < 4; ++mi)
        ah[mi] = *(const short8*)(Eh0 + (cblk * 128 + mi * 16) * D_DIM + dc * 32);
#pragma unroll
      for (int mi = 0; mi < 4; ++mi)
#pragma unroll
        for (int ni = 0; ni < 2; ++ni)
          acc[mi][ni] = __builtin_amdgcn_mfma_f32_16x16x32_bf16(ah[mi], xfrag[ni][dc], acc[mi][ni], 0, 0, 0);
    }
    // distances + running per-lane argmin (code order ascending: cblk->mi->r)
#pragma unroll
    for (int mi = 0; mi < 4; ++mi) {
      float4 en = *(const float4*)&enorm[cblk * 128 + wm * 64 + mi * 16 + q * 4];
      const float* enp = (const float*)&en;
#pragma unroll
      for (int ni = 0; ni < 2; ++ni)
#pragma unroll
        for (int r = 0; r < 4; ++r) {
          float v = fmaf(-2.f, acc[mi][ni][r], enp[r]);
          if (v < bestv[ni]) {
            bestv[ni] = v;
            bestc[ni] = cblk * 128 + wm * 64 + mi * 16 + q * 4 + r;
          }
        }
    }
  }

  // ---- argmin merge: q-groups via shfl, wm halves via LDS ----
#pragma unroll
  for (int ni = 0; ni < 2; ++ni) {
    float bv = bestv[ni];
    int bc = bestc[ni];
#pragma unroll
    for (int off = 16; off <= 32; off <<= 1) {
      float ov = __shfl_xor(bv, off);
      int oc = __shfl_xor(bc, off);
      if (ov < bv || (ov == bv && oc < bc)) { bv = ov; bc = oc; }
    }
    bestv[ni] = bv;
    bestc[ni] = bc;
  }
  if (wm == 0 && q == 0) {
#pragma unroll
    for (int ni = 0; ni < 2; ++ni) {
      bvs[wn * 32 + ni * 16 + l15] = bestv[ni];
      bcs[wn * 32 + ni * 16 + l15] = bestc[ni];
    }
  }
  __syncthreads();
  if (wm == 1 && q == 0) {
#pragma unroll
    for (int ni = 0; ni < 2; ++ni) {
      int s = wn * 32 + ni * 16 + l15;
      if (bestv[ni] < bvs[s]) {  // tie keeps wm0 = smaller code index
        bvs[s] = bestv[ni];
        bcs[s] = bestc[ni];
      }
    }
  }
  // xsq wave-reduce in parallel with the merge
  float xs_ = xsq;
#pragma unroll
  for (int off = 32; off >= 1; off >>= 1) xs_ += __shfl_xor(xs_, off);
  if (lane == 0) lred[wv] = xs_;
  __syncthreads();

  // ---- counts + loss (loss = sum bestval + sum x^2; no fences, G12/R4 lesson) ----
  if (t < 64) {
    atomicAdd(&counts[bcs[t]], 1.0f);
    float v = bvs[t];
#pragma unroll
    for (int off = 32; off >= 1; off >>= 1) v += __shfl_xor(v, off);
    if (t == 0) atomicAdd(lossacc, v + lred[0] + lred[1] + lred[2] + lred[3]);
  }

  // ---- output write: quantized[b][d][hw] = E[best[n]][d], straight from L2 ----
  const int s4 = (t & 15) * 4;
  const int dbase = t >> 4;
  float* Ob = out + b * SMP_B + hw0 + s4;
  const float* E0 = E + bcs[s4 + 0] * D_DIM;
  const float* E1 = E + bcs[s4 + 1] * D_DIM;
  const float* E2 = E + bcs[s4 + 2] * D_DIM;
  const float* E3 = E + bcs[s4 + 3] * D_DIM;
#pragma unroll 4
  for (int p = 0; p < 16; ++p) {
    const int d = dbase + p * 16;
    float4 qv;
    qv.x = E0[d];
    qv.y = E1[d];
    qv.z = E2[d];
    qv.w = E3[d];
    *(float4*)(Ob + d * HW_SZ) = qv;
  }
}

// -------------------------------------------------------------- finalize ----
__global__ __launch_bounds__(256) void vq_finalize(const float* __restrict__ counts,
                                                   const float* __restrict__ lossacc,
                                                   float* __restrict__ out_tail) {
  __shared__ float part[4];
  const int t = threadIdx.x;
  float s = 0.f;
#pragma unroll
  for (int k = t; k < K_EMB; k += 256) {
    float p = counts[k] * (1.0f / 32768.0f);
    s = fmaf(p, logf(p + 1e-10f), s);  // p==0 -> 0*log(1e-10)==0, matches ref
  }
#pragma unroll
  for (int off = 32; off >= 1; off >>= 1) s += __shfl_xor(s, off);
  if ((t & 63) == 0) part[t >> 6] = s;
  __syncthreads();
  if (t == 0) {
    float tot = part[0] + part[1] + part[2] + part[3];
    out_tail[0] = 1.25f * lossacc[0] * (1.0f / 8388608.0f);
    out_tail[1] = expf(-tot);
  }
}

// ---------------------------------------------------------------- launch ----
extern "C" void kernel_launch(void* const* d_in, const int* in_sizes, int n_in,
                              void* d_out, int out_size, void* d_ws, size_t ws_size,
                              hipStream_t stream) {
  const float* X = (const float*)d_in[0];  // [32,256,32,32]
  const float* E = (const float*)d_in[1];  // [1024,256]
  float* out = (float*)d_out;              // 8388608 + 2
  float* ws = (float*)d_ws;

  unsigned short* Ehi = (unsigned short*)ws;  // [1024][256] bf16 = 512 KB
  float* enorm = ws + 131072;                 // [1024]
  float* counts = ws + 132096;                // [1024]
  float* lossa = ws + 133120;                 // [1]  (counts..lossa zeroed by prep_e)

  vq_prep_e<<<128, 256, 0, stream>>>(E, Ehi, enorm, counts);
  vq_main<<<512, 256, 0, stream>>>(X, E, Ehi, enorm, out, counts, lossa);
  vq_finalize<<<1, 256, 0, stream>>>(counts, lossa, out + 8388608);
}